// Round 6
// baseline (504.887 us; speedup 1.0000x reference)
//
#include <hip/hip_runtime.h>
#include <stdint.h>

constexpr int CB   = 4;
constexpr int CS   = 512;
constexpr int CHID = 2048;
constexpr int CNH  = 4;
constexpr int CNM  = 8;
constexpr int CVD  = 2048;   // value dim
constexpr int CHVD = 512;    // per-head value dim
constexpr int CT   = CB * CS;   // 2048 tokens
constexpr int CN4  = 6144;      // q(1024)+k(1024)+v(2048)+g(2048)

typedef __bf16 bf16x8 __attribute__((ext_vector_type(8)));
typedef float  f32x4  __attribute__((ext_vector_type(4)));
typedef unsigned short us4 __attribute__((ext_vector_type(4)));
typedef unsigned short us8 __attribute__((ext_vector_type(8)));

union bfu { us8 u; bf16x8 b; };

__device__ __forceinline__ unsigned short f2bf(float f) {
    union { float f; unsigned int i; } v; v.f = f;
    return (unsigned short)((v.i + 0x7fffu + ((v.i >> 16) & 1u)) >> 16);
}
__device__ __forceinline__ float bf2f(unsigned short u) {
    union { unsigned int i; float f; } v; v.i = ((unsigned int)u) << 16; return v.f;
}
__device__ __forceinline__ float wave_sum(float v) {
    #pragma unroll
    for (int o = 32; o; o >>= 1) v += __shfl_down(v, o, 64);
    return v;
}
__device__ __forceinline__ void async16(const void* g, void* l) {
    __builtin_amdgcn_global_load_lds(
        (const __attribute__((address_space(1))) unsigned int*)g,
        (__attribute__((address_space(3))) unsigned int*)l, 16, 0, 0);
}
__device__ __forceinline__ float sigmoidf(float x) { return 1.f / (1.f + expf(-x)); }
__device__ __forceinline__ float siluf(float x)    { return x / (1.f + expf(-x)); }

// ---------------------------------------------------------------------------
// K0: fused fp32 -> bf16 conversion of all six tensors (1 launch instead of 6)
// quad-index boundaries: x 1048576 | q_w 524288 | k_w 524288 | v_w 1048576 |
//                        g_w 1048576 | o_w 1048576   (total 5242880 quads)
// ---------------------------------------------------------------------------
__global__ __launch_bounds__(256) void cvt_all(
    const float* __restrict__ x,  const float* __restrict__ qw,
    const float* __restrict__ kw, const float* __restrict__ vw,
    const float* __restrict__ gw, const float* __restrict__ ow,
    unsigned short* __restrict__ xb, unsigned short* __restrict__ wb,
    unsigned short* __restrict__ owb)
{
    int i = blockIdx.x * 256 + threadIdx.x;
    const float* src; unsigned short* dst; int local;
    if      (i < 1048576) { src = x;  dst = xb;               local = i; }
    else if (i < 1572864) { src = qw; dst = wb;               local = i - 1048576; }
    else if (i < 2097152) { src = kw; dst = wb + 1024 * CHID; local = i - 1572864; }
    else if (i < 3145728) { src = vw; dst = wb + 2048 * CHID; local = i - 2097152; }
    else if (i < 4194304) { src = gw; dst = wb + 4096 * CHID; local = i - 3145728; }
    else                  { src = ow; dst = owb;              local = i - 4194304; }
    f32x4 v = *(const f32x4*)(src + (size_t)local * 4);
    us4 o;
    o.x = f2bf(v.x); o.y = f2bf(v.y); o.z = f2bf(v.z); o.w = f2bf(v.w);
    *(us4*)(dst + (size_t)local * 4) = o;
}

// ---------------------------------------------------------------------------
// K1: per-token small projections + routing + decay (stores LOG decay)
// ---------------------------------------------------------------------------
__global__ __launch_bounds__(256) void prep_kernel(
    const float* __restrict__ x,
    const float* __restrict__ gate_w,
    const float* __restrict__ b_w,
    const float* __restrict__ a_w,
    const float* __restrict__ A_log,
    const float* __restrict__ dt_bias,
    int*   __restrict__ tok_sel,
    float* __restrict__ tok_w,
    float* __restrict__ tok_beta,
    float* __restrict__ tok_glog)
{
    int t = blockIdx.x, tid = threadIdx.x;
    float acc[16];
    #pragma unroll
    for (int r = 0; r < 16; r++) acc[r] = 0.f;
    for (int k = tid; k < CHID; k += 256) {
        float xv = x[t * CHID + k];
        #pragma unroll
        for (int r = 0; r < 8; r++) acc[r]      += xv * gate_w[r * CHID + k];
        #pragma unroll
        for (int r = 0; r < 4; r++) acc[8 + r]  += xv * b_w[r * CHID + k];
        #pragma unroll
        for (int r = 0; r < 4; r++) acc[12 + r] += xv * a_w[r * CHID + k];
    }
    __shared__ float part[4][16];
    __shared__ float fin[16];
    int lane = tid & 63, wave = tid >> 6;
    #pragma unroll
    for (int r = 0; r < 16; r++) {
        float v = wave_sum(acc[r]);
        if (lane == 0) part[wave][r] = v;
    }
    __syncthreads();
    if (tid < 16) fin[tid] = part[0][tid] + part[1][tid] + part[2][tid] + part[3][tid];
    __syncthreads();
    if (tid == 0) {
        float p[8], mx = -1e30f;
        for (int i = 0; i < 8; i++) { p[i] = fin[i]; if (p[i] > mx) mx = p[i]; }
        float sum = 0.f;
        for (int i = 0; i < 8; i++) { p[i] = expf(p[i] - mx); sum += p[i]; }
        for (int i = 0; i < 8; i++) p[i] /= sum;
        int i0 = 0; float b0 = p[0];
        for (int i = 1; i < 8; i++) if (p[i] > b0) { b0 = p[i]; i0 = i; }
        int i1 = -1; float b1 = -1e30f;
        for (int i = 0; i < 8; i++) { if (i == i0) continue; if (p[i] > b1) { b1 = p[i]; i1 = i; } }
        float wsn = b0 + b1;
        tok_sel[t * 2 + 0] = i0;       tok_sel[t * 2 + 1] = i1;
        tok_w[t * 2 + 0]   = b0 / wsn; tok_w[t * 2 + 1]   = b1 / wsn;
        for (int h = 0; h < 4; h++) {
            float beta = sigmoidf(fin[8 + h]);
            float ar   = fin[12 + h] + dt_bias[h];
            float sp   = (ar > 20.f) ? ar : log1pf(expf(ar));
            float g    = -expf(A_log[h]) * sp;
            tok_beta[t * 4 + h] = beta;
            tok_glog[t * 4 + h] = g;
        }
    }
}

// ---------------------------------------------------------------------------
// K2: build per-(b,m) ordered routed-token lists. grid = 32, block = 512
// ---------------------------------------------------------------------------
__global__ __launch_bounds__(512) void compact_kernel(
    const int* __restrict__ tok_sel, const float* __restrict__ tok_w,
    int* __restrict__ cnt, int* __restrict__ lists, float* __restrict__ wlists)
{
    int p = blockIdx.x;
    int b = p >> 3, m = p & 7;
    int s = threadIdx.x;
    int tok = b * CS + s;
    int s0 = tok_sel[tok * 2 + 0], s1 = tok_sel[tok * 2 + 1];
    int slot = (s0 == m) ? 0 : ((s1 == m) ? 1 : -1);
    bool routed = slot >= 0;
    unsigned long long mask = __ballot(routed);
    int lane = s & 63, wave = s >> 6;
    int pfx = __popcll(mask & ((1ull << lane) - 1ull));
    __shared__ int wcnt[8], woff[8];
    if (lane == 0) wcnt[wave] = (int)__popcll(mask);
    __syncthreads();
    if (threadIdx.x == 0) {
        int o = 0;
        for (int i = 0; i < 8; i++) { woff[i] = o; o += wcnt[i]; }
        cnt[p] = o;
    }
    __syncthreads();
    if (routed) {
        int pos = woff[wave] + pfx;
        lists[p * CS + pos]  = s | (slot << 16);
        wlists[p * CS + pos] = tok_w[tok * 2 + slot];
    }
}

// ---------------------------------------------------------------------------
// K3: fused bf16 GEMM  Cb[T][6144] = x[T][2048] @ Wfused^T   (fp32 out)
// ---------------------------------------------------------------------------
__global__ __launch_bounds__(256) void gemm_qkvg(
    const unsigned short* __restrict__ X,
    const unsigned short* __restrict__ Wf,
    float* __restrict__ Cb)
{
    __shared__ unsigned short As[128 * 32];
    __shared__ unsigned short Bs[128 * 32];
    int tid = threadIdx.x;
    int m0 = blockIdx.x * 128;
    int n0 = blockIdx.y * 128;

    int wave = tid >> 6, lane = tid & 63;
    int wr = wave >> 1, wc = wave & 1;
    int lrow = lane & 15, quad = lane >> 4;

    f32x4 acc[4][4];
    #pragma unroll
    for (int i = 0; i < 4; i++)
        #pragma unroll
        for (int j = 0; j < 4; j++) { f32x4 z = {0.f,0.f,0.f,0.f}; acc[i][j] = z; }

    int srow = tid >> 2;
    int sseg = (tid & 3) * 8;

    for (int k0 = 0; k0 < CHID; k0 += 32) {
        async16(X  + (size_t)(m0 + srow) * CHID + k0 + sseg,      As + wave * 512);
        async16(X  + (size_t)(m0 + 64 + srow) * CHID + k0 + sseg, As + 2048 + wave * 512);
        async16(Wf + (size_t)(n0 + srow) * CHID + k0 + sseg,      Bs + wave * 512);
        async16(Wf + (size_t)(n0 + 64 + srow) * CHID + k0 + sseg, Bs + 2048 + wave * 512);
        __syncthreads();
        bf16x8 afr[4], bfr[4];
        #pragma unroll
        for (int i = 0; i < 4; i++) {
            int ra = wr * 64 + i * 16 + lrow;
            afr[i] = *(const bf16x8*)(As + ra * 32 + quad * 8);
            int rb = wc * 64 + i * 16 + lrow;
            bfr[i] = *(const bf16x8*)(Bs + rb * 32 + quad * 8);
        }
        #pragma unroll
        for (int i = 0; i < 4; i++)
            #pragma unroll
            for (int j = 0; j < 4; j++)
                acc[i][j] = __builtin_amdgcn_mfma_f32_16x16x32_bf16(afr[i], bfr[j], acc[i][j], 0, 0, 0);
        __syncthreads();
    }
    #pragma unroll
    for (int i = 0; i < 4; i++)
        #pragma unroll
        for (int j = 0; j < 4; j++) {
            int gn = n0 + wc * 64 + j * 16 + lrow;
            #pragma unroll
            for (int r = 0; r < 4; r++) {
                int gm = m0 + wr * 64 + i * 16 + quad * 4 + r;
                Cb[(size_t)gm * CN4 + gn] = acc[i][j][r];
            }
        }
}

// ---------------------------------------------------------------------------
// K4: activations: silu+l2norm on q,k -> qkbf (bf16); silu on v (in place)
// qkbf layout: [tok][h][q 256 | k 256]
// ---------------------------------------------------------------------------
__global__ __launch_bounds__(256) void act_qkv(float* __restrict__ Cb,
                                               unsigned short* __restrict__ qkbf)
{
    int t = blockIdx.x, tid = threadIdx.x;
    int lane = tid & 63, wave = tid >> 6;
    __shared__ float red[4];
    for (int h = 0; h < 4; h++) {
        size_t iq = (size_t)t * CN4 + h * 256 + tid;
        size_t ik = iq + 1024;
        float sq = siluf(Cb[iq]);
        float sk = siluf(Cb[ik]);
        float ssq = wave_sum(sq * sq);
        if (lane == 0) red[wave] = ssq;
        __syncthreads();
        float qs = 0.0625f / fmaxf(sqrtf(red[0] + red[1] + red[2] + red[3]), 1e-12f);
        __syncthreads();
        float ssk = wave_sum(sk * sk);
        if (lane == 0) red[wave] = ssk;
        __syncthreads();
        float ks = 1.f / fmaxf(sqrtf(red[0] + red[1] + red[2] + red[3]), 1e-12f);
        __syncthreads();
        qkbf[((size_t)t * 4 + h) * 512 + tid]       = f2bf(sq * qs);
        qkbf[((size_t)t * 4 + h) * 512 + 256 + tid] = f2bf(sk * ks);
        __syncthreads();
    }
    for (int c = tid; c < CVD; c += 256) {
        size_t idx = (size_t)t * CN4 + 2048 + c;
        Cb[idx] = siluf(Cb[idx]);
    }
}

// ---------------------------------------------------------------------------
// K5: CHUNKED gated delta rule (C=32), MFMA + LDS staging.
// grid = 512 blocks: (m,b,h,v-quarter), 512 threads (8 waves).
// Wave owns 16 v-cols; h state = 16 f32x4 accum frags (rows k, cols v).
// 2 blocks/CU (77.9 KB LDS each) -> 16 waves/CU, single scheduling pass.
// ---------------------------------------------------------------------------
__global__ __launch_bounds__(512, 4) void recur_kernel(
    const unsigned short* __restrict__ qkbf,
    const float* __restrict__ Cb,
    const float* __restrict__ tok_beta, const float* __restrict__ tok_glog,
    const int* __restrict__ cnt, const int* __restrict__ lists,
    const float* __restrict__ wlists, float* __restrict__ oslot)
{
    int bx = blockIdx.x;
    int m = bx & 7, b = (bx >> 3) & 3, h = (bx >> 5) & 3, qt = (bx >> 7) & 3;
    int p = b * 8 + m;
    int n = cnt[p];
    int vq = qt * 128;

    int tid = threadIdx.x;
    int wv = tid >> 6, lane = tid & 63;
    int lrow = lane & 15, quad = lane >> 4;

    // LDS ~77.9 KB
    __shared__ __align__(16) unsigned short kq[32 * 512];      // 32 KB swizzled k|q
    __shared__ __align__(16) unsigned short scratch[8 * 1280]; // 20 KB per-wave h0/brhs; overlay Kt[256][40]
    __shared__ float G[64][33];
    __shared__ float BA[32][36];
    __shared__ __align__(16) unsigned short Sld[32][40];
    __shared__ __align__(16) unsigned short Wld[128][40];      // u solved, [v][t]
    __shared__ float metaBeta[32], metaW[32], metaLg[32];
    __shared__ int   metaTok[32], metaSlot[32];

    f32x4 hacc[16];
    #pragma unroll
    for (int i = 0; i < 16; i++) { f32x4 z = {0.f,0.f,0.f,0.f}; hacc[i] = z; }

    for (int c0 = 0; c0 < n; c0 += 32) {
        __syncthreads();

        // ---- S1: chunk metadata + log-decay prefix scan (threads 0..31) ----
        if (tid < 32) {
            int t = tid;
            int idx = c0 + t;
            bool valid = idx < n;
            int eidx = valid ? idx : (n - 1);
            int e = lists[p * CS + eidx];
            int tok = b * CS + (e & 0xffff);
            metaTok[t]  = tok;
            metaSlot[t] = e >> 16;
            metaW[t]    = valid ? wlists[p * CS + eidx] : 0.f;
            metaBeta[t] = valid ? tok_beta[tok * 4 + h] : 0.f;
            float g     = valid ? tok_glog[tok * 4 + h] : 0.f;
            #pragma unroll
            for (int o = 1; o < 32; o <<= 1) {
                float xg = __shfl_up(g, o, 64);
                if (t >= o) g += xg;
            }
            metaLg[t] = g;
        }
        __syncthreads();

        // ---- S1.5: stage k+q of 32 tokens into LDS (async16, xor-swizzle) ----
        {
            #pragma unroll
            for (int r = 0; r < 4; r++) {
                int L = r * 512 + tid;
                int t = L >> 6, sl = L & 63;
                int slog = ((sl & 31) ^ (t & 31)) | (sl & 32);
                int off = (slog < 32) ? (256 + slog * 8) : ((slog - 32) * 8);
                const unsigned short* g = qkbf + ((size_t)metaTok[t] * 4 + h) * 512 + off;
                async16(g, kq + (size_t)(r * 512 + (tid & 448)) * 8);
            }
        }
        __syncthreads();

        // ---- S2: Gram [K;Q] @ K^T. wave wv: M-tile wv>>1, N-tile wv&1 ----
        {
            int mt = wv >> 1, nt = wv & 1;
            int trow = (mt & 1) * 16 + lrow;
            int qflag = (mt >= 2) ? 32 : 0;
            int bcol = nt * 16 + lrow;
            f32x4 g0 = {0.f,0.f,0.f,0.f};
            #pragma unroll
            for (int ks = 0; ks < 8; ks++) {
                int sA = ((ks * 4 + quad) ^ trow) | qflag;
                int sB = (ks * 4 + quad) ^ (bcol & 31);
                bf16x8 af = *(const bf16x8*)(kq + trow * 512 + sA * 8);
                bf16x8 bf = *(const bf16x8*)(kq + bcol * 512 + sB * 8);
                g0 = __builtin_amdgcn_mfma_f32_16x16x32_bf16(af, bf, g0, 0, 0, 0);
            }
            #pragma unroll
            for (int r = 0; r < 4; r++)
                G[mt * 16 + quad * 4 + r][nt * 16 + lrow] = g0[r];
        }

        // ---- S3: h0 -> bf16 (wave-private LDS, 4 phases of 64k),
        //          PQ0 = [K;Q]@h0, stage Brhs ----
        f32x4 pq[4];   // 0,1: K@h0 (pred tiles), 2,3: Q@h0 (out tiles)
        #pragma unroll
        for (int i = 0; i < 4; i++) { f32x4 z = {0.f,0.f,0.f,0.f}; pq[i] = z; }
        {
            unsigned short* hb = scratch + wv * 1280;
            #pragma unroll
            for (int ph = 0; ph < 4; ph++) {
                #pragma unroll
                for (int mi4 = 0; mi4 < 4; mi4++) {
                    f32x4 hv = hacc[ph * 4 + mi4];
                    us4 pk;
                    pk.x = f2bf(hv.x); pk.y = f2bf(hv.y); pk.z = f2bf(hv.z); pk.w = f2bf(hv.w);
                    *(us4*)(hb + lrow * 68 + mi4 * 16 + quad * 4) = pk;
                }
                #pragma unroll
                for (int ks4 = 0; ks4 < 2; ks4++) {
                    bf16x8 b0 = *(const bf16x8*)(hb + lrow * 68 + ks4 * 32 + quad * 8);
                    int segbase = ph * 8 + ks4 * 4 + quad;
                    #pragma unroll
                    for (int mi = 0; mi < 4; mi++) {
                        int trow = (mi & 1) * 16 + lrow;
                        int sA = (segbase ^ trow) | ((mi >= 2) ? 32 : 0);
                        bf16x8 af = *(const bf16x8*)(kq + trow * 512 + sA * 8);
                        pq[mi] = __builtin_amdgcn_mfma_f32_16x16x32_bf16(af, b0, pq[mi], 0, 0, 0);
                    }
                }
            }
            // Brhs[vlocal][t] = beta*(v - gamma*pred0), fp32 stride 36
            float* brhs = (float*)(scratch + wv * 1280);
            #pragma unroll
            for (int mi = 0; mi < 2; mi++) {
                f32x4 outv;
                #pragma unroll
                for (int r = 0; r < 4; r++) {
                    int t = mi * 16 + quad * 4 + r;
                    float vv = Cb[(size_t)metaTok[t] * CN4 + 2048 + h * 512 + vq + wv * 16 + lrow];
                    outv[r] = metaBeta[t] * (vv - __expf(metaLg[t]) * pq[mi][r]);
                }
                *(f32x4*)(brhs + lrow * 36 + mi * 16 + quad * 4) = outv;
            }
        }
        __syncthreads();

        // ---- S4: build BA (fp32, zero-padded) and S (bf16) ----
        for (int idx = tid; idx < 32 * 36; idx += 512) {
            int t = idx / 36, j = idx % 36;
            float v = 0.f;
            if (j < t) v = metaBeta[t] * __expf(metaLg[t] - metaLg[j]) * G[t][j];
            BA[t][j] = v;
        }
        for (int idx = tid; idx < 32 * 32; idx += 512) {
            int t = idx >> 5, j = idx & 31;
            float sv = (j <= t) ? __expf(metaLg[t] - metaLg[j]) * G[32 + t][j] : 0.f;
            Sld[t][j] = f2bf(sv);
        }
        __syncthreads();

        // ---- S5: forward substitution u = (I+BA)^{-1} rhs (threads 0..127) ----
        if (tid < 128) {
            int v = tid;
            const float* br = (const float*)(scratch + (v >> 4) * 1280) + (size_t)(v & 15) * 36;
            float u[32];
            #pragma unroll
            for (int s4 = 0; s4 < 8; s4++) {
                f32x4 t4 = *(const f32x4*)(br + s4 * 4);
                u[s4 * 4 + 0] = t4.x; u[s4 * 4 + 1] = t4.y;
                u[s4 * 4 + 2] = t4.z; u[s4 * 4 + 3] = t4.w;
            }
            #pragma unroll
            for (int t = 1; t < 32; t++) {
                float acc = 0.f;
                #pragma unroll
                for (int jb = 0; jb * 4 < t; jb++) {
                    f32x4 ba = *(const f32x4*)&BA[t][jb * 4];
                    acc += ba.x * u[jb * 4 + 0] + ba.y * u[jb * 4 + 1]
                         + ba.z * u[jb * 4 + 2] + ba.w * u[jb * 4 + 3];
                }
                u[t] -= acc;
            }
            #pragma unroll
            for (int s8 = 0; s8 < 4; s8++) {
                us8 w8;
                #pragma unroll
                for (int e = 0; e < 8; e++) w8[e] = f2bf(u[s8 * 8 + e]);
                *(us8*)(&Wld[v][s8 * 8]) = w8;
            }
        }
        __syncthreads();

        // ---- S6: build Kt ([kcol][t] stride 40, overlays scratch) + O-GEMM ----
        {
            int tl = tid & 31, kseg = tid >> 5;   // kseg 0..15, 16 kcols each
            unsigned short* Kt = scratch;
            #pragma unroll
            for (int j8 = 0; j8 < 2; j8++) {
                int slot = (kseg * 2 + j8) ^ tl;
                us8 kv = *(const us8*)(kq + tl * 512 + slot * 8);
                #pragma unroll
                for (int e = 0; e < 8; e++)
                    Kt[(kseg * 16 + j8 * 8 + e) * 40 + tl] = kv[e];
            }
        }
        {
            f32x4 oacc[2];
            { f32x4 z = {0.f,0.f,0.f,0.f}; oacc[0] = z; oacc[1] = z; }
            bf16x8 sa0 = *(const bf16x8*)(&Sld[lrow][quad * 8]);
            bf16x8 sa1 = *(const bf16x8*)(&Sld[16 + lrow][quad * 8]);
            bf16x8 wb8 = *(const bf16x8*)(&Wld[wv * 16 + lrow][quad * 8]);
            oacc[0] = __builtin_amdgcn_mfma_f32_16x16x32_bf16(sa0, wb8, oacc[0], 0, 0, 0);
            oacc[1] = __builtin_amdgcn_mfma_f32_16x16x32_bf16(sa1, wb8, oacc[1], 0, 0, 0);
            #pragma unroll
            for (int mi = 0; mi < 2; mi++)
                #pragma unroll
                for (int r = 0; r < 4; r++) {
                    int t = mi * 16 + quad * 4 + r;
                    if (c0 + t < n) {
                        float val = __expf(metaLg[t]) * pq[2 + mi][r] + oacc[mi][r];
                        size_t off = (((size_t)metaSlot[t] * CT + metaTok[t]) * CNH + h) * CHVD
                                   + vq + wv * 16 + lrow;
                        oslot[off] = metaW[t] * val;
                    }
                }
        }
        __syncthreads();

        // ---- S7: h <- gamma_C * h + K^T @ (decay-scaled u) ----
        {
            float gC = __expf(metaLg[31]);
            float rs[8];
            #pragma unroll
            for (int e = 0; e < 8; e++) rs[e] = __expf(metaLg[31] - metaLg[quad * 8 + e]);
            bfu wu; wu.b = *(const bf16x8*)(&Wld[wv * 16 + lrow][quad * 8]);
            us8 sc;
            #pragma unroll
            for (int e = 0; e < 8; e++) sc[e] = f2bf(bf2f(wu.u[e]) * rs[e]);
            bfu ubu; ubu.u = sc;
            bf16x8 ub = ubu.b;
            const unsigned short* Kt = scratch;
            #pragma unroll
            for (int mi = 0; mi < 16; mi++) {
                bf16x8 ka = *(const bf16x8*)(Kt + (mi * 16 + lrow) * 40 + quad * 8);
                hacc[mi] *= gC;
                hacc[mi] = __builtin_amdgcn_mfma_f32_16x16x32_bf16(ka, ub, hacc[mi], 0, 0, 0);
            }
        }
    }
}

// ---------------------------------------------------------------------------
// K6: combine slots + RMSNorm + sigmoid(gproj) gate -> act bf16
// ---------------------------------------------------------------------------
__global__ __launch_bounds__(256) void act_gate(
    const float* __restrict__ oslot, const float* __restrict__ Cb,
    const float* __restrict__ o_norm_w, unsigned short* __restrict__ actb)
{
    int t = blockIdx.x, tid = threadIdx.x;
    int lane = tid & 63, wave = tid >> 6;
    __shared__ float red[4];
    for (int h = 0; h < 4; h++) {
        size_t b0 = (((size_t)0 * CT + t) * CNH + h) * CHVD;
        size_t b1 = (((size_t)1 * CT + t) * CNH + h) * CHVD;
        float v0 = oslot[b0 + tid]       + oslot[b1 + tid];
        float v1 = oslot[b0 + 256 + tid] + oslot[b1 + 256 + tid];
        float ss = wave_sum(v0 * v0 + v1 * v1);
        if (lane == 0) red[wave] = ss;
        __syncthreads();
        float tot = red[0] + red[1] + red[2] + red[3];
        float rinv = 1.f / sqrtf(tot / 512.f + 1e-6f);
        float g0 = Cb[(size_t)t * CN4 + 4096 + h * CHVD + tid];
        float g1 = Cb[(size_t)t * CN4 + 4096 + h * CHVD + 256 + tid];
        float r0 = v0 * rinv * o_norm_w[tid]       * sigmoidf(g0);
        float r1 = v1 * rinv * o_norm_w[256 + tid] * sigmoidf(g1);
        actb[(size_t)t * CVD + h * CHVD + tid]       = f2bf(r0);
        actb[(size_t)t * CVD + h * CHVD + 256 + tid] = f2bf(r1);
        __syncthreads();
    }
}

// ---------------------------------------------------------------------------
// K7: output GEMM  d_out[T][2048] = act[T][2048] @ o_w^T   (fp32 out)
// ---------------------------------------------------------------------------
__global__ __launch_bounds__(256) void gemm_o(
    const unsigned short* __restrict__ A,
    const unsigned short* __restrict__ W,
    float* __restrict__ Out)
{
    __shared__ unsigned short As[128 * 32];
    __shared__ unsigned short Bs[128 * 32];
    int tid = threadIdx.x;
    int m0 = blockIdx.x * 128;
    int n0 = blockIdx.y * 128;
    int wave = tid >> 6, lane = tid & 63;
    int wr = wave >> 1, wc = wave & 1;
    int lrow = lane & 15, quad = lane >> 4;

    f32x4 acc[4][4];
    #pragma unroll
    for (int i = 0; i < 4; i++)
        #pragma unroll
        for (int j = 0; j < 4; j++) { f32x4 z = {0.f,0.f,0.f,0.f}; acc[i][j] = z; }

    int srow = tid >> 2;
    int sseg = (tid & 3) * 8;

    for (int k0 = 0; k0 < CVD; k0 += 32) {
        async16(A + (size_t)(m0 + srow) * CVD + k0 + sseg,      As + wave * 512);
        async16(A + (size_t)(m0 + 64 + srow) * CVD + k0 + sseg, As + 2048 + wave * 512);
        async16(W + (size_t)(n0 + srow) * CVD + k0 + sseg,      Bs + wave * 512);
        async16(W + (size_t)(n0 + 64 + srow) * CVD + k0 + sseg, Bs + 2048 + wave * 512);
        __syncthreads();
        bf16x8 afr[4], bfr[4];
        #pragma unroll
        for (int i = 0; i < 4; i++) {
            int ra = wr * 64 + i * 16 + lrow;
            afr[i] = *(const bf16x8*)(As + ra * 32 + quad * 8);
            int rb = wc * 64 + i * 16 + lrow;
            bfr[i] = *(const bf16x8*)(Bs + rb * 32 + quad * 8);
        }
        #pragma unroll
        for (int i = 0; i < 4; i++)
            #pragma unroll
            for (int j = 0; j < 4; j++)
                acc[i][j] = __builtin_amdgcn_mfma_f32_16x16x32_bf16(afr[i], bfr[j], acc[i][j], 0, 0, 0);
        __syncthreads();
    }
    #pragma unroll
    for (int i = 0; i < 4; i++)
        #pragma unroll
        for (int j = 0; j < 4; j++) {
            int gn = n0 + wc * 64 + j * 16 + lrow;
            #pragma unroll
            for (int r = 0; r < 4; r++) {
                int gm = m0 + wr * 64 + i * 16 + quad * 4 + r;
                Out[(size_t)gm * CHID + gn] = acc[i][j][r];
            }
        }
}

// ---------------------------------------------------------------------------
extern "C" void kernel_launch(void* const* d_in, const int* in_sizes, int n_in,
                              void* d_out, int out_size, void* d_ws, size_t ws_size,
                              hipStream_t stream)
{
    const float* x      = (const float*)d_in[0];
    const float* gate_w = (const float*)d_in[1];
    const float* q_w    = (const float*)d_in[2];
    const float* k_w    = (const float*)d_in[3];
    const float* v_w    = (const float*)d_in[4];
    const float* b_w    = (const float*)d_in[5];
    const float* a_w    = (const float*)d_in[6];
    const float* g_w    = (const float*)d_in[7];
    const float* o_w    = (const float*)d_in[8];
    const float* A_log  = (const float*)d_in[9];
    const float* dt_b   = (const float*)d_in[10];
    const float* onw    = (const float*)d_in[11];

    char* ws = (char*)d_ws;
    float*          Cb       = (float*)(ws + 0);                  // 50331648 B
    float*          oslot    = (float*)(ws + 50331648);           // 33554432 B
    unsigned short* actb     = (unsigned short*)(ws + 83886080);  //  8388608 B
    unsigned short* qkbf     = actb;                              // overlay: qkbf dies before actb born
    unsigned short* xb       = (unsigned short*)(ws + 92274688);  //  8388608 B
    unsigned short* wb       = (unsigned short*)(ws + 100663296); // 25165824 B
    unsigned short* owb      = (unsigned short*)(ws + 125829120); //  8388608 B
    int*            tok_sel  = (int*)(ws + 134217728);
    float*          tok_w    = (float*)(ws + 134234112);
    float*          tok_beta = (float*)(ws + 134250496);
    float*          tok_glog = (float*)(ws + 134283264);
    int*            cnt      = (int*)(ws + 134316032);
    int*            lists    = (int*)(ws + 134316160);
    float*          wlists   = (float*)(ws + 134381696);

    cvt_all<<<dim3(20480), dim3(256), 0, stream>>>(x, q_w, k_w, v_w, g_w, o_w,
                                                   xb, wb, owb);
    prep_kernel<<<dim3(CT), dim3(256), 0, stream>>>(x, gate_w, b_w, a_w, A_log, dt_b,
                                                    tok_sel, tok_w, tok_beta, tok_glog);
    compact_kernel<<<dim3(CB * CNM), dim3(512), 0, stream>>>(tok_sel, tok_w, cnt, lists, wlists);
    gemm_qkvg<<<dim3(16, 48), dim3(256), 0, stream>>>(xb, wb, Cb);
    act_qkv<<<dim3(CT), dim3(256), 0, stream>>>(Cb, qkbf);
    recur_kernel<<<dim3(512), dim3(512), 0, stream>>>(qkbf, Cb, tok_beta, tok_glog,
                                                      cnt, lists, wlists, oslot);
    act_gate<<<dim3(CT), dim3(256), 0, stream>>>(oslot, Cb, onw, actb);
    gemm_o<<<dim3(16, 16), dim3(256), 0, stream>>>(actb, owb, (float*)d_out);
}

// Round 7
// 453.669 us; speedup vs baseline: 1.1129x; 1.1129x over previous
//
#include <hip/hip_runtime.h>
#include <stdint.h>

constexpr int CB   = 4;
constexpr int CS   = 512;
constexpr int CHID = 2048;
constexpr int CNH  = 4;
constexpr int CNM  = 8;
constexpr int CVD  = 2048;   // value dim
constexpr int CHVD = 512;    // per-head value dim
constexpr int CT   = CB * CS;   // 2048 tokens
constexpr int CN4  = 6144;      // q(1024)+k(1024)+v(2048)+g(2048)

typedef __bf16 bf16x8 __attribute__((ext_vector_type(8)));
typedef float  f32x4  __attribute__((ext_vector_type(4)));
typedef unsigned short us4 __attribute__((ext_vector_type(4)));
typedef unsigned short us8 __attribute__((ext_vector_type(8)));

union bfu { us8 u; bf16x8 b; };

__device__ __forceinline__ unsigned short f2bf(float f) {
    union { float f; unsigned int i; } v; v.f = f;
    return (unsigned short)((v.i + 0x7fffu + ((v.i >> 16) & 1u)) >> 16);
}
__device__ __forceinline__ float bf2f(unsigned short u) {
    union { unsigned int i; float f; } v; v.i = ((unsigned int)u) << 16; return v.f;
}
__device__ __forceinline__ float wave_sum(float v) {
    #pragma unroll
    for (int o = 32; o; o >>= 1) v += __shfl_down(v, o, 64);
    return v;
}
__device__ __forceinline__ void async16(const void* g, void* l) {
    __builtin_amdgcn_global_load_lds(
        (const __attribute__((address_space(1))) unsigned int*)g,
        (__attribute__((address_space(3))) unsigned int*)l, 16, 0, 0);
}
__device__ __forceinline__ float sigmoidf(float x) { return 1.f / (1.f + expf(-x)); }
__device__ __forceinline__ float siluf(float x)    { return x / (1.f + expf(-x)); }

// ---------------------------------------------------------------------------
// K0: fused fp32 -> bf16 conversion of all six tensors (1 launch)
// ---------------------------------------------------------------------------
__global__ __launch_bounds__(256) void cvt_all(
    const float* __restrict__ x,  const float* __restrict__ qw,
    const float* __restrict__ kw, const float* __restrict__ vw,
    const float* __restrict__ gw, const float* __restrict__ ow,
    unsigned short* __restrict__ xb, unsigned short* __restrict__ wb,
    unsigned short* __restrict__ owb)
{
    int i = blockIdx.x * 256 + threadIdx.x;
    const float* src; unsigned short* dst; int local;
    if      (i < 1048576) { src = x;  dst = xb;               local = i; }
    else if (i < 1572864) { src = qw; dst = wb;               local = i - 1048576; }
    else if (i < 2097152) { src = kw; dst = wb + 1024 * CHID; local = i - 1572864; }
    else if (i < 3145728) { src = vw; dst = wb + 2048 * CHID; local = i - 2097152; }
    else if (i < 4194304) { src = gw; dst = wb + 4096 * CHID; local = i - 3145728; }
    else                  { src = ow; dst = owb;              local = i - 4194304; }
    f32x4 v = *(const f32x4*)(src + (size_t)local * 4);
    us4 o;
    o.x = f2bf(v.x); o.y = f2bf(v.y); o.z = f2bf(v.z); o.w = f2bf(v.w);
    *(us4*)(dst + (size_t)local * 4) = o;
}

// ---------------------------------------------------------------------------
// K1: per-token small projections + routing + decay (stores LOG decay)
// ---------------------------------------------------------------------------
__global__ __launch_bounds__(256) void prep_kernel(
    const float* __restrict__ x,
    const float* __restrict__ gate_w,
    const float* __restrict__ b_w,
    const float* __restrict__ a_w,
    const float* __restrict__ A_log,
    const float* __restrict__ dt_bias,
    int*   __restrict__ tok_sel,
    float* __restrict__ tok_w,
    float* __restrict__ tok_beta,
    float* __restrict__ tok_glog)
{
    int t = blockIdx.x, tid = threadIdx.x;
    float acc[16];
    #pragma unroll
    for (int r = 0; r < 16; r++) acc[r] = 0.f;
    for (int k = tid; k < CHID; k += 256) {
        float xv = x[t * CHID + k];
        #pragma unroll
        for (int r = 0; r < 8; r++) acc[r]      += xv * gate_w[r * CHID + k];
        #pragma unroll
        for (int r = 0; r < 4; r++) acc[8 + r]  += xv * b_w[r * CHID + k];
        #pragma unroll
        for (int r = 0; r < 4; r++) acc[12 + r] += xv * a_w[r * CHID + k];
    }
    __shared__ float part[4][16];
    __shared__ float fin[16];
    int lane = tid & 63, wave = tid >> 6;
    #pragma unroll
    for (int r = 0; r < 16; r++) {
        float v = wave_sum(acc[r]);
        if (lane == 0) part[wave][r] = v;
    }
    __syncthreads();
    if (tid < 16) fin[tid] = part[0][tid] + part[1][tid] + part[2][tid] + part[3][tid];
    __syncthreads();
    if (tid == 0) {
        float p[8], mx = -1e30f;
        for (int i = 0; i < 8; i++) { p[i] = fin[i]; if (p[i] > mx) mx = p[i]; }
        float sum = 0.f;
        for (int i = 0; i < 8; i++) { p[i] = expf(p[i] - mx); sum += p[i]; }
        for (int i = 0; i < 8; i++) p[i] /= sum;
        int i0 = 0; float b0 = p[0];
        for (int i = 1; i < 8; i++) if (p[i] > b0) { b0 = p[i]; i0 = i; }
        int i1 = -1; float b1 = -1e30f;
        for (int i = 0; i < 8; i++) { if (i == i0) continue; if (p[i] > b1) { b1 = p[i]; i1 = i; } }
        float wsn = b0 + b1;
        tok_sel[t * 2 + 0] = i0;       tok_sel[t * 2 + 1] = i1;
        tok_w[t * 2 + 0]   = b0 / wsn; tok_w[t * 2 + 1]   = b1 / wsn;
        for (int h = 0; h < 4; h++) {
            float beta = sigmoidf(fin[8 + h]);
            float ar   = fin[12 + h] + dt_bias[h];
            float sp   = (ar > 20.f) ? ar : log1pf(expf(ar));
            float g    = -expf(A_log[h]) * sp;
            tok_beta[t * 4 + h] = beta;
            tok_glog[t * 4 + h] = g;
        }
    }
}

// ---------------------------------------------------------------------------
// K2: build per-(b,m) ordered routed-token lists. grid = 32, block = 512
// ---------------------------------------------------------------------------
__global__ __launch_bounds__(512) void compact_kernel(
    const int* __restrict__ tok_sel, const float* __restrict__ tok_w,
    int* __restrict__ cnt, int* __restrict__ lists, float* __restrict__ wlists)
{
    int p = blockIdx.x;
    int b = p >> 3, m = p & 7;
    int s = threadIdx.x;
    int tok = b * CS + s;
    int s0 = tok_sel[tok * 2 + 0], s1 = tok_sel[tok * 2 + 1];
    int slot = (s0 == m) ? 0 : ((s1 == m) ? 1 : -1);
    bool routed = slot >= 0;
    unsigned long long mask = __ballot(routed);
    int lane = s & 63, wave = s >> 6;
    int pfx = __popcll(mask & ((1ull << lane) - 1ull));
    __shared__ int wcnt[8], woff[8];
    if (lane == 0) wcnt[wave] = (int)__popcll(mask);
    __syncthreads();
    if (threadIdx.x == 0) {
        int o = 0;
        for (int i = 0; i < 8; i++) { woff[i] = o; o += wcnt[i]; }
        cnt[p] = o;
    }
    __syncthreads();
    if (routed) {
        int pos = woff[wave] + pfx;
        lists[p * CS + pos]  = s | (slot << 16);
        wlists[p * CS + pos] = tok_w[tok * 2 + slot];
    }
}

// ---------------------------------------------------------------------------
// K3: fused bf16 GEMM  Cb[T][6144] = x[T][2048] @ Wfused^T   (fp32 out)
// ---------------------------------------------------------------------------
__global__ __launch_bounds__(256) void gemm_qkvg(
    const unsigned short* __restrict__ X,
    const unsigned short* __restrict__ Wf,
    float* __restrict__ Cb)
{
    __shared__ unsigned short As[128 * 32];
    __shared__ unsigned short Bs[128 * 32];
    int tid = threadIdx.x;
    int m0 = blockIdx.x * 128;
    int n0 = blockIdx.y * 128;

    int wave = tid >> 6, lane = tid & 63;
    int wr = wave >> 1, wc = wave & 1;
    int lrow = lane & 15, quad = lane >> 4;

    f32x4 acc[4][4];
    #pragma unroll
    for (int i = 0; i < 4; i++)
        #pragma unroll
        for (int j = 0; j < 4; j++) { f32x4 z = {0.f,0.f,0.f,0.f}; acc[i][j] = z; }

    int srow = tid >> 2;
    int sseg = (tid & 3) * 8;

    for (int k0 = 0; k0 < CHID; k0 += 32) {
        async16(X  + (size_t)(m0 + srow) * CHID + k0 + sseg,      As + wave * 512);
        async16(X  + (size_t)(m0 + 64 + srow) * CHID + k0 + sseg, As + 2048 + wave * 512);
        async16(Wf + (size_t)(n0 + srow) * CHID + k0 + sseg,      Bs + wave * 512);
        async16(Wf + (size_t)(n0 + 64 + srow) * CHID + k0 + sseg, Bs + 2048 + wave * 512);
        __syncthreads();
        bf16x8 afr[4], bfr[4];
        #pragma unroll
        for (int i = 0; i < 4; i++) {
            int ra = wr * 64 + i * 16 + lrow;
            afr[i] = *(const bf16x8*)(As + ra * 32 + quad * 8);
            int rb = wc * 64 + i * 16 + lrow;
            bfr[i] = *(const bf16x8*)(Bs + rb * 32 + quad * 8);
        }
        #pragma unroll
        for (int i = 0; i < 4; i++)
            #pragma unroll
            for (int j = 0; j < 4; j++)
                acc[i][j] = __builtin_amdgcn_mfma_f32_16x16x32_bf16(afr[i], bfr[j], acc[i][j], 0, 0, 0);
        __syncthreads();
    }
    #pragma unroll
    for (int i = 0; i < 4; i++)
        #pragma unroll
        for (int j = 0; j < 4; j++) {
            int gn = n0 + wc * 64 + j * 16 + lrow;
            #pragma unroll
            for (int r = 0; r < 4; r++) {
                int gm = m0 + wr * 64 + i * 16 + quad * 4 + r;
                Cb[(size_t)gm * CN4 + gn] = acc[i][j][r];
            }
        }
}

// ---------------------------------------------------------------------------
// K4: activations: silu+l2norm on q,k -> qkbf (bf16); silu on v (in place)
// qkbf layout: [tok][h][q 256 | k 256]
// ---------------------------------------------------------------------------
__global__ __launch_bounds__(256) void act_qkv(float* __restrict__ Cb,
                                               unsigned short* __restrict__ qkbf)
{
    int t = blockIdx.x, tid = threadIdx.x;
    int lane = tid & 63, wave = tid >> 6;
    __shared__ float red[4];
    for (int h = 0; h < 4; h++) {
        size_t iq = (size_t)t * CN4 + h * 256 + tid;
        size_t ik = iq + 1024;
        float sq = siluf(Cb[iq]);
        float sk = siluf(Cb[ik]);
        float ssq = wave_sum(sq * sq);
        if (lane == 0) red[wave] = ssq;
        __syncthreads();
        float qs = 0.0625f / fmaxf(sqrtf(red[0] + red[1] + red[2] + red[3]), 1e-12f);
        __syncthreads();
        float ssk = wave_sum(sk * sk);
        if (lane == 0) red[wave] = ssk;
        __syncthreads();
        float ks = 1.f / fmaxf(sqrtf(red[0] + red[1] + red[2] + red[3]), 1e-12f);
        __syncthreads();
        qkbf[((size_t)t * 4 + h) * 512 + tid]       = f2bf(sq * qs);
        qkbf[((size_t)t * 4 + h) * 512 + 256 + tid] = f2bf(sk * ks);
        __syncthreads();
    }
    for (int c = tid; c < CVD; c += 256) {
        size_t idx = (size_t)t * CN4 + 2048 + c;
        Cb[idx] = siluf(Cb[idx]);
    }
}

// ---------------------------------------------------------------------------
// K5: CHUNKED gated delta rule (C=32), MFMA + LDS staging.
// grid = 512 blocks: (m,b,h,v-quarter), 512 threads (8 waves).
// Wave owns 16 v-cols; h state = 16 f32x4 accum frags (rows k, cols v).
// NOTE: __launch_bounds__(512) with NO min-waves arg — (512,4) capped VGPRs
// at 64 and spilled hacc to scratch (R6: 614 MB HBM, 202 µs). At ~128 VGPR
// the HW hosts 16 waves/CU = 2 blocks/CU; LDS 79.9 KB x 2 fits 160 KB.
// ---------------------------------------------------------------------------
__global__ __launch_bounds__(512) void recur_kernel(
    const unsigned short* __restrict__ qkbf,
    const float* __restrict__ Cb,
    const float* __restrict__ tok_beta, const float* __restrict__ tok_glog,
    const int* __restrict__ cnt, const int* __restrict__ lists,
    const float* __restrict__ wlists, float* __restrict__ oslot)
{
    int bx = blockIdx.x;
    int m = bx & 7, b = (bx >> 3) & 3, h = (bx >> 5) & 3, qt = (bx >> 7) & 3;
    int p = b * 8 + m;
    int n = cnt[p];
    int vq = qt * 128;

    int tid = threadIdx.x;
    int wv = tid >> 6, lane = tid & 63;
    int lrow = lane & 15, quad = lane >> 4;

    // LDS ~77.9 KB
    __shared__ __align__(16) unsigned short kq[32 * 512];      // 32 KB swizzled k|q
    __shared__ __align__(16) unsigned short scratch[8 * 1280]; // 20 KB per-wave h0/brhs; overlay Kt[256][40]
    __shared__ float G[64][33];
    __shared__ float BA[32][36];
    __shared__ __align__(16) unsigned short Sld[32][40];
    __shared__ __align__(16) unsigned short Wld[128][40];      // u solved, [v][t]
    __shared__ float metaBeta[32], metaW[32], metaLg[32];
    __shared__ int   metaTok[32], metaSlot[32];

    f32x4 hacc[16];
    #pragma unroll
    for (int i = 0; i < 16; i++) { f32x4 z = {0.f,0.f,0.f,0.f}; hacc[i] = z; }

    for (int c0 = 0; c0 < n; c0 += 32) {
        __syncthreads();

        // ---- S1: chunk metadata + log-decay prefix scan (threads 0..31) ----
        if (tid < 32) {
            int t = tid;
            int idx = c0 + t;
            bool valid = idx < n;
            int eidx = valid ? idx : (n - 1);
            int e = lists[p * CS + eidx];
            int tok = b * CS + (e & 0xffff);
            metaTok[t]  = tok;
            metaSlot[t] = e >> 16;
            metaW[t]    = valid ? wlists[p * CS + eidx] : 0.f;
            metaBeta[t] = valid ? tok_beta[tok * 4 + h] : 0.f;
            float g     = valid ? tok_glog[tok * 4 + h] : 0.f;
            #pragma unroll
            for (int o = 1; o < 32; o <<= 1) {
                float xg = __shfl_up(g, o, 64);
                if (t >= o) g += xg;
            }
            metaLg[t] = g;
        }
        __syncthreads();

        // ---- S1.5: stage k+q of 32 tokens into LDS (async16, xor-swizzle) ----
        {
            #pragma unroll
            for (int r = 0; r < 4; r++) {
                int L = r * 512 + tid;
                int t = L >> 6, sl = L & 63;
                int slog = ((sl & 31) ^ (t & 31)) | (sl & 32);
                int off = (slog < 32) ? (256 + slog * 8) : ((slog - 32) * 8);
                const unsigned short* g = qkbf + ((size_t)metaTok[t] * 4 + h) * 512 + off;
                async16(g, kq + (size_t)(r * 512 + (tid & 448)) * 8);
            }
        }
        __syncthreads();

        // ---- S2: Gram [K;Q] @ K^T. wave wv: M-tile wv>>1, N-tile wv&1 ----
        {
            int mt = wv >> 1, nt = wv & 1;
            int trow = (mt & 1) * 16 + lrow;
            int qflag = (mt >= 2) ? 32 : 0;
            int bcol = nt * 16 + lrow;
            f32x4 g0 = {0.f,0.f,0.f,0.f};
            #pragma unroll
            for (int ks = 0; ks < 8; ks++) {
                int sA = ((ks * 4 + quad) ^ trow) | qflag;
                int sB = (ks * 4 + quad) ^ (bcol & 31);
                bf16x8 af = *(const bf16x8*)(kq + trow * 512 + sA * 8);
                bf16x8 bf = *(const bf16x8*)(kq + bcol * 512 + sB * 8);
                g0 = __builtin_amdgcn_mfma_f32_16x16x32_bf16(af, bf, g0, 0, 0, 0);
            }
            #pragma unroll
            for (int r = 0; r < 4; r++)
                G[mt * 16 + quad * 4 + r][nt * 16 + lrow] = g0[r];
        }

        // ---- S3: h0 -> bf16 (wave-private LDS, 4 phases of 64k),
        //          PQ0 = [K;Q]@h0, stage Brhs ----
        f32x4 pq[4];   // 0,1: K@h0 (pred tiles), 2,3: Q@h0 (out tiles)
        #pragma unroll
        for (int i = 0; i < 4; i++) { f32x4 z = {0.f,0.f,0.f,0.f}; pq[i] = z; }
        {
            unsigned short* hb = scratch + wv * 1280;
            #pragma unroll
            for (int ph = 0; ph < 4; ph++) {
                #pragma unroll
                for (int mi4 = 0; mi4 < 4; mi4++) {
                    f32x4 hv = hacc[ph * 4 + mi4];
                    us4 pk;
                    pk.x = f2bf(hv.x); pk.y = f2bf(hv.y); pk.z = f2bf(hv.z); pk.w = f2bf(hv.w);
                    *(us4*)(hb + lrow * 68 + mi4 * 16 + quad * 4) = pk;
                }
                #pragma unroll
                for (int ks4 = 0; ks4 < 2; ks4++) {
                    bf16x8 b0 = *(const bf16x8*)(hb + lrow * 68 + ks4 * 32 + quad * 8);
                    int segbase = ph * 8 + ks4 * 4 + quad;
                    #pragma unroll
                    for (int mi = 0; mi < 4; mi++) {
                        int trow = (mi & 1) * 16 + lrow;
                        int sA = (segbase ^ trow) | ((mi >= 2) ? 32 : 0);
                        bf16x8 af = *(const bf16x8*)(kq + trow * 512 + sA * 8);
                        pq[mi] = __builtin_amdgcn_mfma_f32_16x16x32_bf16(af, b0, pq[mi], 0, 0, 0);
                    }
                }
            }
            // Brhs[vlocal][t] = beta*(v - gamma*pred0), fp32 stride 36
            float* brhs = (float*)(scratch + wv * 1280);
            #pragma unroll
            for (int mi = 0; mi < 2; mi++) {
                f32x4 outv;
                #pragma unroll
                for (int r = 0; r < 4; r++) {
                    int t = mi * 16 + quad * 4 + r;
                    float vv = Cb[(size_t)metaTok[t] * CN4 + 2048 + h * 512 + vq + wv * 16 + lrow];
                    outv[r] = metaBeta[t] * (vv - __expf(metaLg[t]) * pq[mi][r]);
                }
                *(f32x4*)(brhs + lrow * 36 + mi * 16 + quad * 4) = outv;
            }
        }
        __syncthreads();

        // ---- S4: build BA (fp32, zero-padded) and S (bf16) ----
        for (int idx = tid; idx < 32 * 36; idx += 512) {
            int t = idx / 36, j = idx % 36;
            float v = 0.f;
            if (j < t) v = metaBeta[t] * __expf(metaLg[t] - metaLg[j]) * G[t][j];
            BA[t][j] = v;
        }
        for (int idx = tid; idx < 32 * 32; idx += 512) {
            int t = idx >> 5, j = idx & 31;
            float sv = (j <= t) ? __expf(metaLg[t] - metaLg[j]) * G[32 + t][j] : 0.f;
            Sld[t][j] = f2bf(sv);
        }
        __syncthreads();

        // ---- S5: forward substitution u = (I+BA)^{-1} rhs (threads 0..127) ----
        if (tid < 128) {
            int v = tid;
            const float* br = (const float*)(scratch + (v >> 4) * 1280) + (size_t)(v & 15) * 36;
            float u[32];
            #pragma unroll
            for (int s4 = 0; s4 < 8; s4++) {
                f32x4 t4 = *(const f32x4*)(br + s4 * 4);
                u[s4 * 4 + 0] = t4.x; u[s4 * 4 + 1] = t4.y;
                u[s4 * 4 + 2] = t4.z; u[s4 * 4 + 3] = t4.w;
            }
            #pragma unroll
            for (int t = 1; t < 32; t++) {
                float acc = 0.f;
                #pragma unroll
                for (int jb = 0; jb * 4 < t; jb++) {
                    f32x4 ba = *(const f32x4*)&BA[t][jb * 4];
                    acc += ba.x * u[jb * 4 + 0] + ba.y * u[jb * 4 + 1]
                         + ba.z * u[jb * 4 + 2] + ba.w * u[jb * 4 + 3];
                }
                u[t] -= acc;
            }
            #pragma unroll
            for (int s8 = 0; s8 < 4; s8++) {
                us8 w8;
                #pragma unroll
                for (int e = 0; e < 8; e++) w8[e] = f2bf(u[s8 * 8 + e]);
                *(us8*)(&Wld[v][s8 * 8]) = w8;
            }
        }
        __syncthreads();

        // ---- S6: build Kt ([kcol][t] stride 40, overlays scratch) + O-GEMM ----
        {
            int tl = tid & 31, kseg = tid >> 5;   // kseg 0..15, 16 kcols each
            unsigned short* Kt = scratch;
            #pragma unroll
            for (int j8 = 0; j8 < 2; j8++) {
                int slot = (kseg * 2 + j8) ^ tl;
                us8 kv = *(const us8*)(kq + tl * 512 + slot * 8);
                #pragma unroll
                for (int e = 0; e < 8; e++)
                    Kt[(kseg * 16 + j8 * 8 + e) * 40 + tl] = kv[e];
            }
        }
        {
            f32x4 oacc[2];
            { f32x4 z = {0.f,0.f,0.f,0.f}; oacc[0] = z; oacc[1] = z; }
            bf16x8 sa0 = *(const bf16x8*)(&Sld[lrow][quad * 8]);
            bf16x8 sa1 = *(const bf16x8*)(&Sld[16 + lrow][quad * 8]);
            bf16x8 wb8 = *(const bf16x8*)(&Wld[wv * 16 + lrow][quad * 8]);
            oacc[0] = __builtin_amdgcn_mfma_f32_16x16x32_bf16(sa0, wb8, oacc[0], 0, 0, 0);
            oacc[1] = __builtin_amdgcn_mfma_f32_16x16x32_bf16(sa1, wb8, oacc[1], 0, 0, 0);
            #pragma unroll
            for (int mi = 0; mi < 2; mi++)
                #pragma unroll
                for (int r = 0; r < 4; r++) {
                    int t = mi * 16 + quad * 4 + r;
                    if (c0 + t < n) {
                        float val = __expf(metaLg[t]) * pq[2 + mi][r] + oacc[mi][r];
                        size_t off = (((size_t)metaSlot[t] * CT + metaTok[t]) * CNH + h) * CHVD
                                   + vq + wv * 16 + lrow;
                        oslot[off] = metaW[t] * val;
                    }
                }
        }
        __syncthreads();

        // ---- S7: h <- gamma_C * h + K^T @ (decay-scaled u) ----
        {
            float gC = __expf(metaLg[31]);
            float rs[8];
            #pragma unroll
            for (int e = 0; e < 8; e++) rs[e] = __expf(metaLg[31] - metaLg[quad * 8 + e]);
            bfu wu; wu.b = *(const bf16x8*)(&Wld[wv * 16 + lrow][quad * 8]);
            us8 sc;
            #pragma unroll
            for (int e = 0; e < 8; e++) sc[e] = f2bf(bf2f(wu.u[e]) * rs[e]);
            bfu ubu; ubu.u = sc;
            bf16x8 ub = ubu.b;
            const unsigned short* Kt = scratch;
            #pragma unroll
            for (int mi = 0; mi < 16; mi++) {
                bf16x8 ka = *(const bf16x8*)(Kt + (mi * 16 + lrow) * 40 + quad * 8);
                hacc[mi] *= gC;
                hacc[mi] = __builtin_amdgcn_mfma_f32_16x16x32_bf16(ka, ub, hacc[mi], 0, 0, 0);
            }
        }
    }
}

// ---------------------------------------------------------------------------
// K6: combine slots + RMSNorm + sigmoid(gproj) gate -> act bf16
// ---------------------------------------------------------------------------
__global__ __launch_bounds__(256) void act_gate(
    const float* __restrict__ oslot, const float* __restrict__ Cb,
    const float* __restrict__ o_norm_w, unsigned short* __restrict__ actb)
{
    int t = blockIdx.x, tid = threadIdx.x;
    int lane = tid & 63, wave = tid >> 6;
    __shared__ float red[4];
    for (int h = 0; h < 4; h++) {
        size_t b0 = (((size_t)0 * CT + t) * CNH + h) * CHVD;
        size_t b1 = (((size_t)1 * CT + t) * CNH + h) * CHVD;
        float v0 = oslot[b0 + tid]       + oslot[b1 + tid];
        float v1 = oslot[b0 + 256 + tid] + oslot[b1 + 256 + tid];
        float ss = wave_sum(v0 * v0 + v1 * v1);
        if (lane == 0) red[wave] = ss;
        __syncthreads();
        float tot = red[0] + red[1] + red[2] + red[3];
        float rinv = 1.f / sqrtf(tot / 512.f + 1e-6f);
        float g0 = Cb[(size_t)t * CN4 + 4096 + h * CHVD + tid];
        float g1 = Cb[(size_t)t * CN4 + 4096 + h * CHVD + 256 + tid];
        float r0 = v0 * rinv * o_norm_w[tid]       * sigmoidf(g0);
        float r1 = v1 * rinv * o_norm_w[256 + tid] * sigmoidf(g1);
        actb[(size_t)t * CVD + h * CHVD + tid]       = f2bf(r0);
        actb[(size_t)t * CVD + h * CHVD + 256 + tid] = f2bf(r1);
        __syncthreads();
    }
}

// ---------------------------------------------------------------------------
// K7: output GEMM  d_out[T][2048] = act[T][2048] @ o_w^T   (fp32 out)
// ---------------------------------------------------------------------------
__global__ __launch_bounds__(256) void gemm_o(
    const unsigned short* __restrict__ A,
    const unsigned short* __restrict__ W,
    float* __restrict__ Out)
{
    __shared__ unsigned short As[128 * 32];
    __shared__ unsigned short Bs[128 * 32];
    int tid = threadIdx.x;
    int m0 = blockIdx.x * 128;
    int n0 = blockIdx.y * 128;
    int wave = tid >> 6, lane = tid & 63;
    int wr = wave >> 1, wc = wave & 1;
    int lrow = lane & 15, quad = lane >> 4;

    f32x4 acc[4][4];
    #pragma unroll
    for (int i = 0; i < 4; i++)
        #pragma unroll
        for (int j = 0; j < 4; j++) { f32x4 z = {0.f,0.f,0.f,0.f}; acc[i][j] = z; }

    int srow = tid >> 2;
    int sseg = (tid & 3) * 8;

    for (int k0 = 0; k0 < CVD; k0 += 32) {
        async16(A + (size_t)(m0 + srow) * CVD + k0 + sseg,      As + wave * 512);
        async16(A + (size_t)(m0 + 64 + srow) * CVD + k0 + sseg, As + 2048 + wave * 512);
        async16(W + (size_t)(n0 + srow) * CVD + k0 + sseg,      Bs + wave * 512);
        async16(W + (size_t)(n0 + 64 + srow) * CVD + k0 + sseg, Bs + 2048 + wave * 512);
        __syncthreads();
        bf16x8 afr[4], bfr[4];
        #pragma unroll
        for (int i = 0; i < 4; i++) {
            int ra = wr * 64 + i * 16 + lrow;
            afr[i] = *(const bf16x8*)(As + ra * 32 + quad * 8);
            int rb = wc * 64 + i * 16 + lrow;
            bfr[i] = *(const bf16x8*)(Bs + rb * 32 + quad * 8);
        }
        #pragma unroll
        for (int i = 0; i < 4; i++)
            #pragma unroll
            for (int j = 0; j < 4; j++)
                acc[i][j] = __builtin_amdgcn_mfma_f32_16x16x32_bf16(afr[i], bfr[j], acc[i][j], 0, 0, 0);
        __syncthreads();
    }
    #pragma unroll
    for (int i = 0; i < 4; i++)
        #pragma unroll
        for (int j = 0; j < 4; j++) {
            int gn = n0 + wc * 64 + j * 16 + lrow;
            #pragma unroll
            for (int r = 0; r < 4; r++) {
                int gm = m0 + wr * 64 + i * 16 + quad * 4 + r;
                Out[(size_t)gm * CHID + gn] = acc[i][j][r];
            }
        }
}

// ---------------------------------------------------------------------------
extern "C" void kernel_launch(void* const* d_in, const int* in_sizes, int n_in,
                              void* d_out, int out_size, void* d_ws, size_t ws_size,
                              hipStream_t stream)
{
    const float* x      = (const float*)d_in[0];
    const float* gate_w = (const float*)d_in[1];
    const float* q_w    = (const float*)d_in[2];
    const float* k_w    = (const float*)d_in[3];
    const float* v_w    = (const float*)d_in[4];
    const float* b_w    = (const float*)d_in[5];
    const float* a_w    = (const float*)d_in[6];
    const float* g_w    = (const float*)d_in[7];
    const float* o_w    = (const float*)d_in[8];
    const float* A_log  = (const float*)d_in[9];
    const float* dt_b   = (const float*)d_in[10];
    const float* onw    = (const float*)d_in[11];

    char* ws = (char*)d_ws;
    float*          Cb       = (float*)(ws + 0);                  // 50331648 B
    float*          oslot    = (float*)(ws + 50331648);           // 33554432 B
    unsigned short* actb     = (unsigned short*)(ws + 83886080);  //  8388608 B
    unsigned short* qkbf     = actb;                              // overlay: qkbf dies before actb born
    unsigned short* xb       = (unsigned short*)(ws + 92274688);  //  8388608 B
    unsigned short* wb       = (unsigned short*)(ws + 100663296); // 25165824 B
    unsigned short* owb      = (unsigned short*)(ws + 125829120); //  8388608 B
    int*            tok_sel  = (int*)(ws + 134217728);
    float*          tok_w    = (float*)(ws + 134234112);
    float*          tok_beta = (float*)(ws + 134250496);
    float*          tok_glog = (float*)(ws + 134283264);
    int*            cnt      = (int*)(ws + 134316032);
    int*            lists    = (int*)(ws + 134316160);
    float*          wlists   = (float*)(ws + 134381696);

    cvt_all<<<dim3(20480), dim3(256), 0, stream>>>(x, q_w, k_w, v_w, g_w, o_w,
                                                   xb, wb, owb);
    prep_kernel<<<dim3(CT), dim3(256), 0, stream>>>(x, gate_w, b_w, a_w, A_log, dt_b,
                                                    tok_sel, tok_w, tok_beta, tok_glog);
    compact_kernel<<<dim3(CB * CNM), dim3(512), 0, stream>>>(tok_sel, tok_w, cnt, lists, wlists);
    gemm_qkvg<<<dim3(16, 48), dim3(256), 0, stream>>>(xb, wb, Cb);
    act_qkv<<<dim3(CT), dim3(256), 0, stream>>>(Cb, qkbf);
    recur_kernel<<<dim3(512), dim3(512), 0, stream>>>(qkbf, Cb, tok_beta, tok_glog,
                                                      cnt, lists, wlists, oslot);
    act_gate<<<dim3(CT), dim3(256), 0, stream>>>(oslot, Cb, onw, actb);
    gemm_o<<<dim3(16, 16), dim3(256), 0, stream>>>(actb, owb, (float*)d_out);
}